// Round 1
// baseline (823.244 us; speedup 1.0000x reference)
//
#include <hip/hip_runtime.h>
#include <math.h>

typedef __attribute__((ext_vector_type(8))) __bf16 bf16x8;
typedef __attribute__((ext_vector_type(4))) __bf16 bf16x4;
typedef __attribute__((ext_vector_type(2))) __bf16 bf16x2;
typedef __attribute__((ext_vector_type(4))) float f32x4;

#define MFMA16(a, b, c) __builtin_amdgcn_mfma_f32_16x16x32_bf16(a, b, c, 0, 0, 0)

typedef const __attribute__((address_space(1))) unsigned int* gas_t;
typedef __attribute__((address_space(3))) unsigned int* las_t;

__device__ __forceinline__ void g2lds16(const __bf16* g, __bf16* l) {
    __builtin_amdgcn_global_load_lds((gas_t)(const void*)g, (las_t)(void*)l, 16, 0, 0);
}

// ---------------------------------------------------------------- pack fp32->bf16
__global__ void pack_bf16(const float* __restrict__ src, __bf16* __restrict__ dst, int n4) {
    int idx = blockIdx.x * 256 + threadIdx.x;
    if (idx < n4) {
        float4 f = *(const float4*)(src + (size_t)idx * 4);
        bf16x4 o;
        o.x = (__bf16)f.x; o.y = (__bf16)f.y; o.z = (__bf16)f.z; o.w = (__bf16)f.w;
        *(bf16x4*)(dst + (size_t)idx * 4) = o;
    }
}

// ---------------------------------------------------------------- 256x256 8-phase GEMM (m201 template)
// C = A·B^T + bias. A: MxK bf16 rm. B: NxK bf16 rm. M,N % 256 == 0, K % 128 == 0.
// 8 waves (2M x 4N), per-wave output 128x64. BK=64, double-buffered LDS (128 KiB, 1 block/CU).
// LDS halves are wave-read-order aligned:
//   A half h: global rows {p*128 + h*64 + r}  (h = mf>>2 for frag mf)   rh = p*64 + r
//   B half h: global rows {p*64  + h*32 + r}  (h = nf>>1 for frag nf)   rh = p*32 + r
// T2 swizzle: elem ^= (rh&7)<<3, applied on global SOURCE at stage + on ds_read addr (rule 21).
// T3/T4: per K-tile 4 phases {Q(Ae,Be),Q(Ae,Bo),Q(Ao,Bo),Q(Ao,Be)}; one half-tile staged per
// phase; counted vmcnt(6) at phases 4/8 only (3 half-tiles in flight across barriers).
// Stage targets always have last ds_read >= 1 phase earlier (drained by barrier+lgkmcnt).

#define STAGE_A(bufi, hh, tt) do {                                                     \
    _Pragma("unroll")                                                                  \
    for (int l = 0; l < 2; ++l) {                                                      \
        int c = (l << 9) + tid, rh = c >> 3;                                           \
        int esw = ((c & 7) << 3) ^ ((rh & 7) << 3);                                    \
        int gm = m0 + ((rh >> 6) << 7) + ((hh) << 6) + (rh & 63);                      \
        g2lds16(A + (size_t)gm * K + ((tt) << 6) + esw, &As[bufi][hh][c << 3]);        \
    } } while (0)

#define STAGE_B(bufi, hh, tt) do {                                                     \
    _Pragma("unroll")                                                                  \
    for (int l = 0; l < 2; ++l) {                                                      \
        int c = (l << 9) + tid, rh = c >> 3;                                           \
        int esw = ((c & 7) << 3) ^ ((rh & 7) << 3);                                    \
        int gn = n0 + ((rh >> 5) << 6) + ((hh) << 5) + (rh & 31);                      \
        g2lds16(B + (size_t)gn * K + ((tt) << 6) + esw, &Bs[bufi][hh][c << 3]);        \
    } } while (0)

#define READ_A(bufi, hh) do {                                                          \
    _Pragma("unroll")                                                                  \
    for (int m2 = 0; m2 < 4; ++m2) {                                                   \
        _Pragma("unroll")                                                              \
        for (int kk = 0; kk < 2; ++kk)                                                 \
            af[m2][kk] = *(const bf16x8*)&As[bufi][hh][                                \
                (((wm << 6) + (m2 << 4) + lm) << 6) + (((kk << 5) + q8) ^ swz)];       \
    } } while (0)

#define READ_B(dst, bufi, hh) do {                                                     \
    _Pragma("unroll")                                                                  \
    for (int n2 = 0; n2 < 2; ++n2) {                                                   \
        _Pragma("unroll")                                                              \
        for (int kk = 0; kk < 2; ++kk)                                                 \
            dst[n2][kk] = *(const bf16x8*)&Bs[bufi][hh][                               \
                (((wn << 5) + (n2 << 4) + lm) << 6) + (((kk << 5) + q8) ^ swz)];       \
    } } while (0)

#define MMA_Q(mh, bvar, nh) do {                                                       \
    __builtin_amdgcn_s_setprio(1);                                                     \
    _Pragma("unroll")                                                                  \
    for (int m2 = 0; m2 < 4; ++m2) {                                                   \
        _Pragma("unroll")                                                              \
        for (int n2 = 0; n2 < 2; ++n2) {                                               \
            _Pragma("unroll")                                                          \
            for (int kk = 0; kk < 2; ++kk)                                             \
                acc[(mh) * 4 + m2][(nh) * 2 + n2] =                                    \
                    MFMA16(af[m2][kk], bvar[n2][kk], acc[(mh) * 4 + m2][(nh) * 2 + n2]); \
    } }                                                                                \
    __builtin_amdgcn_s_setprio(0); } while (0)

#define BAR __builtin_amdgcn_s_barrier()
#define MID do { BAR; asm volatile("s_waitcnt lgkmcnt(0)" ::: "memory"); } while (0)
#define VMW(n) asm volatile("s_waitcnt vmcnt(" #n ")" ::: "memory")
#define NOPS ((void)0)

// one K-tile = 4 phases; S1..S4 are per-phase stage ops, W4 the phase-4 vm-wait
#define TILE4(bufi, S1, S2, S3, S4, W4) do {                                           \
    READ_A(bufi, 0); READ_B(be, bufi, 0);                                              \
    S1; MID; MMA_Q(0, be, 0); BAR;                                                     \
    READ_B(bo, bufi, 1);                                                               \
    S2; MID; MMA_Q(0, bo, 1); BAR;                                                     \
    READ_A(bufi, 1);                                                                   \
    S3; MID; MMA_Q(1, bo, 1); BAR;                                                     \
    S4; W4; BAR; MMA_Q(1, be, 0); BAR; } while (0)

template <typename OutT>
__global__ __launch_bounds__(512, 2)
void gemm256_bt_bias(const __bf16* __restrict__ A, const __bf16* __restrict__ B,
                     const float* __restrict__ bias, OutT* __restrict__ C,
                     int M, int N, int K) {
    __shared__ __align__(16) __bf16 As[2][2][8192];
    __shared__ __align__(16) __bf16 Bs[2][2][8192];

    const int tid = threadIdx.x;
    const int lane = tid & 63, wave = tid >> 6;
    const int lm = lane & 15, quad = lane >> 4, q8 = quad << 3;
    const int wm = wave >> 2, wn = wave & 3;
    const int swz = (lm & 7) << 3;

    // T1: XCD-aware bijective swizzle (grid sizes are % 8 == 0)
    const int nwg = gridDim.x;
    const int wg = (blockIdx.x & 7) * (nwg >> 3) + (blockIdx.x >> 3);
    const int nbx = N >> 8;
    const int m0 = (wg / nbx) << 8;
    const int n0 = (wg % nbx) << 8;

    const int NT = K >> 6, ITER = NT >> 1;

    f32x4 acc[8][4] = {};
    bf16x8 af[4][2], be[2][2], bo[2][2];

    // prologue: tile 0 complete + 3 halves of tile 1; vmcnt(6) keeps tile-1 halves in flight
    STAGE_A(0, 0, 0); STAGE_B(0, 0, 0); STAGE_B(0, 1, 0); STAGE_A(0, 1, 0);
    STAGE_A(1, 0, 1); STAGE_B(1, 0, 1); STAGE_B(1, 1, 1);
    VMW(6);
    BAR;

#pragma unroll 1
    for (int i = 0; i < ITER - 1; ++i) {
        const int b = 2 * i + 1, t2 = 2 * i + 2, t3 = 2 * i + 3;
        TILE4(0, STAGE_A(1, 1, b),  STAGE_A(0, 0, t2), STAGE_B(0, 0, t2), STAGE_B(0, 1, t2), VMW(6));
        TILE4(1, STAGE_A(0, 1, t2), STAGE_A(1, 0, t3), STAGE_B(1, 0, t3), STAGE_B(1, 1, t3), VMW(6));
    }
    // drain iteration: tiles NT-2 (buf0) and NT-1 (buf1)
    {
        const int b = NT - 1;
        TILE4(0, STAGE_A(1, 1, b), NOPS, NOPS, NOPS, VMW(0));
        TILE4(1, NOPS, NOPS, NOPS, NOPS, NOPS);
    }

    // epilogue: same C/D mapping as verified baseline (rows quad*4+r, cols lm)
#pragma unroll
    for (int nf = 0; nf < 4; ++nf) {
        const int col = n0 + (wn << 6) + (nf << 4) + lm;
        const float bj = bias[col];
#pragma unroll
        for (int mf = 0; mf < 8; ++mf) {
            const int mb = m0 + (wm << 7) + (mf << 4) + (quad << 2);
#pragma unroll
            for (int r = 0; r < 4; ++r)
                C[(size_t)(mb + r) * N + col] = (OutT)(acc[mf][nf][r] + bj);
        }
    }
}

// ---------------------------------------------------------------- RMSNorm + 3D RoPE on q,k (in place, bf16)
__global__ void rmsrope(__bf16* __restrict__ qkv, const float* __restrict__ qw,
                        const float* __restrict__ kw) {
    int bn = blockIdx.x;            // b*2048 + n
    int n = bn & 2047;
    int tid = threadIdx.x, wave = tid >> 6, lane = tid & 63;
    int d0 = lane * 2;
    int t = n >> 8, hp = (n >> 4) & 15, wp = n & 15;
    float pos, fi;
    if (d0 < 44)      { pos = (float)t;  fi = (float)(d0 >> 1) * (2.0f / 44.0f); }
    else if (d0 < 86) { pos = (float)hp; fi = (float)((d0 - 44) >> 1) * (2.0f / 42.0f); }
    else              { pos = (float)wp; fi = (float)((d0 - 86) >> 1) * (2.0f / 42.0f); }
    float freq = expf(-fi * 9.210340371976184f);  // 10000^-fi
    float ang = pos * freq, sn, cs;
    sincosf(ang, &sn, &cs);
    float w0q = qw[d0], w1q = qw[d0 + 1], w0k = kw[d0], w1k = kw[d0 + 1];

    for (int h = wave; h < 24; h += 4) {
        size_t base = (size_t)bn * 9216 + h * 128 + d0;
        {
            bf16x2 xv = *(bf16x2*)(qkv + base);
            float x0 = (float)xv.x, x1 = (float)xv.y;
            float ss = x0 * x0 + x1 * x1;
            for (int m = 1; m < 64; m <<= 1) ss += __shfl_xor(ss, m, 64);
            float rr = rsqrtf(ss * (1.0f / 128.0f) + 1e-6f);
            float y0 = x0 * rr * w0q, y1 = x1 * rr * w1q;
            bf16x2 st; st.x = (__bf16)(y0 * cs - y1 * sn); st.y = (__bf16)(y1 * cs + y0 * sn);
            *(bf16x2*)(qkv + base) = st;
        }
        {
            bf16x2 xv = *(bf16x2*)(qkv + base + 3072);
            float x0 = (float)xv.x, x1 = (float)xv.y;
            float ss = x0 * x0 + x1 * x1;
            for (int m = 1; m < 64; m <<= 1) ss += __shfl_xor(ss, m, 64);
            float rr = rsqrtf(ss * (1.0f / 128.0f) + 1e-6f);
            float y0 = x0 * rr * w0k, y1 = x1 * rr * w1k;
            bf16x2 st; st.x = (__bf16)(y0 * cs - y1 * sn); st.y = (__bf16)(y1 * cs + y0 * sn);
            *(bf16x2*)(qkv + base + 3072) = st;
        }
    }
}

// ---------------------------------------------------------------- flash attention (S^T orientation)
// qkv: [4096][9216] bf16 (q/k normed+roped in place; v at 6144+h*128). O: [B][N][C] bf16.
// S^T = K·Q^T: lane holds qrow = lane&15, keys = quad*4+reg (+16j) -> per-lane softmax stats.
__global__ __launch_bounds__(256, 2)
void flash(const __bf16* __restrict__ qkv, __bf16* __restrict__ Oo) {
    __shared__ __align__(16) __bf16 Ks[64 * 136];   // [key][d]
    __shared__ __align__(16) __bf16 VTs[128 * 72];  // [d][key]
    __shared__ __align__(16) __bf16 Ps[128 * 72];   // [q row][key]
    int bh = blockIdx.x >> 4, qt = blockIdx.x & 15;
    int b = bh / 24, h = bh % 24;
    int q0 = qt * 128;
    int tid = threadIdx.x, wave = tid >> 6, lane = tid & 63;
    int lm = lane & 15, q8 = (lane >> 4) * 8, quad = lane >> 4;
    int wb = wave * 32;
    const float sc = 0.08838834764831845f;  // 1/sqrt(128)

    // Q fragments: rows wb+i*16+lm of this q-tile (used as MFMA B operand)
    bf16x8 qf[2][4];
    for (int i = 0; i < 2; ++i)
        for (int kk = 0; kk < 4; ++kk)
            qf[i][kk] = *(const bf16x8*)(qkv + (size_t)(b * 2048 + q0 + wb + i * 16 + lm) * 9216
                                         + h * 128 + kk * 32 + q8);

    float mrow[2] = {-__builtin_inff(), -__builtin_inff()};
    float lrow[2] = {0.f, 0.f};
    f32x4 oacc[2][8] = {};   // oacc[i][ct]: d = ct*16+quad*4+reg, qrow = wb+i*16+lm

    for (int nt = 0; nt < 32; ++nt) {
        int n0 = nt * 64;
        __syncthreads();
        for (int r = 0; r < 4; ++r) {
            int c = r * 256 + tid;                  // 0..1023
            int krow = c >> 4, kch = (c & 15) * 8;  // K: 64 x 16 chunks
            *(uint4*)(Ks + krow * 136 + kch) =
                *(const uint4*)(qkv + (size_t)(b * 2048 + n0 + krow) * 9216 + 3072 + h * 128 + kch);
            int vkey = c & 63, vch = (c >> 6) * 8;  // V: transpose on stage
            bf16x8 vv = *(const bf16x8*)(qkv + (size_t)(b * 2048 + n0 + vkey) * 9216 + 6144 + h * 128 + vch);
            for (int j = 0; j < 8; ++j)
                VTs[(vch + j) * 72 + vkey] = vv[j];
        }
        __syncthreads();

        // S^T = K Q^T : s[i][j] holds keys j*16+quad*4+reg for qrow wb+i*16+lm
        f32x4 s[2][4] = {};
        for (int kk = 0; kk < 4; ++kk) {
            bf16x8 bk[4];
            for (int j = 0; j < 4; ++j)
                bk[j] = *(const bf16x8*)(Ks + (j * 16 + lm) * 136 + kk * 32 + q8);
            for (int i = 0; i < 2; ++i)
                for (int j = 0; j < 4; ++j)
                    s[i][j] = MFMA16(bk[j], qf[i][kk], s[i][j]);
        }
        // online softmax: all 16 key-values for a row are in-lane; cross-quad = 2 shuffles
        for (int i = 0; i < 2; ++i) {
            float mx = -__builtin_inff();
            for (int j = 0; j < 4; ++j)
                for (int r = 0; r < 4; ++r)
                    mx = fmaxf(mx, s[i][j][r]);
            mx *= sc;
            mx = fmaxf(mx, __shfl_xor(mx, 16, 64));
            mx = fmaxf(mx, __shfl_xor(mx, 32, 64));
            float mn = fmaxf(mrow[i], mx);
            float alpha = __expf(mrow[i] - mn);
            mrow[i] = mn;
            float rs = 0.f;
            for (int j = 0; j < 4; ++j) {
                bf16x4 pw;
                for (int r = 0; r < 4; ++r) {
                    float p = __expf(s[i][j][r] * sc - mn);
                    rs += p;
                    pw[r] = (__bf16)p;
                }
                *(bf16x4*)(Ps + (wb + i * 16 + lm) * 72 + j * 16 + quad * 4) = pw;
            }
            rs += __shfl_xor(rs, 16, 64);
            rs += __shfl_xor(rs, 32, 64);
            lrow[i] = lrow[i] * alpha + rs;
            if (__any(alpha != 1.0f))
                for (int ct = 0; ct < 8; ++ct) oacc[i][ct] *= alpha;
        }
        // O^T += V^T P^T (P rows wb..wb+31 are wave-private)
        for (int kk = 0; kk < 2; ++kk) {
            bf16x8 ap[2];
            for (int i = 0; i < 2; ++i)
                ap[i] = *(const bf16x8*)(Ps + (wb + i * 16 + lm) * 72 + kk * 32 + q8);
            for (int ct = 0; ct < 8; ++ct) {
                bf16x8 bv = *(const bf16x8*)(VTs + (ct * 16 + lm) * 72 + kk * 32 + q8);
                for (int i = 0; i < 2; ++i)
                    oacc[i][ct] = MFMA16(bv, ap[i], oacc[i][ct]);
            }
        }
    }
    // epilogue: O /= l; lane owns qrow = wb+i*16+lm, d = ct*16+quad*4+[0..3]
    for (int i = 0; i < 2; ++i) {
        float inv = 1.0f / lrow[i];
        int row = q0 + wb + i * 16 + lm;
        size_t base = ((size_t)b * 2048 + row) * 3072 + h * 128 + quad * 4;
        for (int ct = 0; ct < 8; ++ct) {
            bf16x4 ov;
            for (int r = 0; r < 4; ++r) ov[r] = (__bf16)(oacc[i][ct][r] * inv);
            *(bf16x4*)(Oo + base + ct * 16) = ov;
        }
    }
}

// ---------------------------------------------------------------- launch
extern "C" void kernel_launch(void* const* d_in, const int* in_sizes, int n_in,
                              void* d_out, int out_size, void* d_ws, size_t ws_size,
                              hipStream_t stream) {
    const float* x      = (const float*)d_in[0];
    const float* qkv_w  = (const float*)d_in[1];
    const float* qkv_b  = (const float*)d_in[2];
    const float* qnw    = (const float*)d_in[3];
    const float* knw    = (const float*)d_in[4];
    const float* proj_w = (const float*)d_in[5];
    const float* proj_b = (const float*)d_in[6];
    float* out = (float*)d_out;
    char* ws = (char*)d_ws;

    // ws layout (bytes), total 176,160,768
    __bf16* xb   = (__bf16*)(ws + 0);           //  25,165,824  x bf16 (dead after gemm1)
    __bf16* attn = (__bf16*)(ws + 0);           //  alias: flash output [4096][3072] bf16
    __bf16* w1b  = (__bf16*)(ws + 25165824);    //  56,623,104  qkv_w bf16
    __bf16* w2b  = (__bf16*)(ws + 81788928);    //  18,874,368  proj_w bf16
    __bf16* qkvb = (__bf16*)(ws + 100663296);   //  75,497,472  qkv bf16 [4096][9216]

    pack_bf16<<<12288, 256, 0, stream>>>(x, xb, 3145728);
    pack_bf16<<<27648, 256, 0, stream>>>(qkv_w, w1b, 7077888);
    pack_bf16<<<9216, 256, 0, stream>>>(proj_w, w2b, 2359296);

    // QKV: [4096,3072] x [9216,3072]^T -> grid 16*36 = 576 blocks (%8==0)
    gemm256_bt_bias<__bf16><<<576, 512, 0, stream>>>(xb, w1b, qkv_b, qkvb, 4096, 9216, 3072);

    rmsrope<<<4096, 256, 0, stream>>>(qkvb, qnw, knw);

    flash<<<768, 256, 0, stream>>>(qkvb, attn);

    // proj: [4096,3072] x [3072,3072]^T -> grid 16*12 = 192 blocks (%8==0)
    gemm256_bt_bias<float><<<192, 512, 0, stream>>>(attn, w2b, proj_b, out, 4096, 3072, 3072);
}

// Round 2
// 822.905 us; speedup vs baseline: 1.0004x; 1.0004x over previous
//
#include <hip/hip_runtime.h>
#include <math.h>

typedef __attribute__((ext_vector_type(8))) __bf16 bf16x8;
typedef __attribute__((ext_vector_type(4))) __bf16 bf16x4;
typedef __attribute__((ext_vector_type(2))) __bf16 bf16x2;
typedef __attribute__((ext_vector_type(4))) float f32x4;

#define MFMA16(a, b, c) __builtin_amdgcn_mfma_f32_16x16x32_bf16(a, b, c, 0, 0, 0)

typedef const __attribute__((address_space(1))) unsigned int* gas_t;
typedef __attribute__((address_space(3))) unsigned int* las_t;

__device__ __forceinline__ void g2lds16(const __bf16* g, __bf16* l) {
    __builtin_amdgcn_global_load_lds((gas_t)(const void*)g, (las_t)(void*)l, 16, 0, 0);
}

// ---------------------------------------------------------------- pack fp32->bf16
__global__ void pack_bf16(const float* __restrict__ src, __bf16* __restrict__ dst, int n4) {
    int idx = blockIdx.x * 256 + threadIdx.x;
    if (idx < n4) {
        float4 f = *(const float4*)(src + (size_t)idx * 4);
        bf16x4 o;
        o.x = (__bf16)f.x; o.y = (__bf16)f.y; o.z = (__bf16)f.z; o.w = (__bf16)f.w;
        *(bf16x4*)(dst + (size_t)idx * 4) = o;
    }
}

// ---------------------------------------------------------------- 256x256 8-phase GEMM
// C = A·B^T + bias. A: MxK bf16 rm. B: NxK bf16 rm. M,N % 256 == 0, K % 128 == 0.
// 8 waves (2M x 4N), per-wave output 128x64. BK=64, double-buffered LDS (128 KiB, 1 block/CU).
// Stage order per iter (2 loads each): s1=A(1,1,t1) s2=A(0,0,t2) s3=B(0,0,t2) s4=B(0,1,t2)
//                                      s5=A(0,1,t2) s6=A(1,0,t3) s7=B(1,0,t3) s8=B(1,1,t3)
// Every half is consumed 6-7 phases after issue -> uniform per-phase vmcnt(10) (5 halves in
// flight) completes exactly the half needed 1-2 phases later, waiting only on loads issued
// 6 phases (~3600 cyc) earlier. (Round-1's vmcnt(6)@phases 4/8 waited on loads 0-3 phases
// old -> exposed full memory latency every 4th phase; MfmaUtil 31%.)
// Each trailing BAR is preceded by a "memory"-clobbered asm (VMW) so next-phase ds_reads
// cannot be hoisted across the cross-wave sync point.

#define STAGE_A(bufi, hh, tt) do {                                                     \
    _Pragma("unroll")                                                                  \
    for (int l = 0; l < 2; ++l) {                                                      \
        int c = (l << 9) + tid, rh = c >> 3;                                           \
        int esw = ((c & 7) << 3) ^ ((rh & 7) << 3);                                    \
        int gm = m0 + ((rh >> 6) << 7) + ((hh) << 6) + (rh & 63);                      \
        g2lds16(A + (size_t)gm * K + ((tt) << 6) + esw, &As[bufi][hh][c << 3]);        \
    } } while (0)

#define STAGE_B(bufi, hh, tt) do {                                                     \
    _Pragma("unroll")                                                                  \
    for (int l = 0; l < 2; ++l) {                                                      \
        int c = (l << 9) + tid, rh = c >> 3;                                           \
        int esw = ((c & 7) << 3) ^ ((rh & 7) << 3);                                    \
        int gn = n0 + ((rh >> 5) << 6) + ((hh) << 5) + (rh & 31);                      \
        g2lds16(B + (size_t)gn * K + ((tt) << 6) + esw, &Bs[bufi][hh][c << 3]);        \
    } } while (0)

#define READ_A(bufi, hh) do {                                                          \
    _Pragma("unroll")                                                                  \
    for (int m2 = 0; m2 < 4; ++m2) {                                                   \
        _Pragma("unroll")                                                              \
        for (int kk = 0; kk < 2; ++kk)                                                 \
            af[m2][kk] = *(const bf16x8*)&As[bufi][hh][                                \
                (((wm << 6) + (m2 << 4) + lm) << 6) + (((kk << 5) + q8) ^ swz)];       \
    } } while (0)

#define READ_B(dst, bufi, hh) do {                                                     \
    _Pragma("unroll")                                                                  \
    for (int n2 = 0; n2 < 2; ++n2) {                                                   \
        _Pragma("unroll")                                                              \
        for (int kk = 0; kk < 2; ++kk)                                                 \
            dst[n2][kk] = *(const bf16x8*)&Bs[bufi][hh][                               \
                (((wn << 5) + (n2 << 4) + lm) << 6) + (((kk << 5) + q8) ^ swz)];       \
    } } while (0)

#define MMA_Q(mh, bvar, nh) do {                                                       \
    __builtin_amdgcn_s_setprio(1);                                                     \
    _Pragma("unroll")                                                                  \
    for (int m2 = 0; m2 < 4; ++m2) {                                                   \
        _Pragma("unroll")                                                              \
        for (int n2 = 0; n2 < 2; ++n2) {                                               \
            _Pragma("unroll")                                                          \
            for (int kk = 0; kk < 2; ++kk)                                             \
                acc[(mh) * 4 + m2][(nh) * 2 + n2] =                                    \
                    MFMA16(af[m2][kk], bvar[n2][kk], acc[(mh) * 4 + m2][(nh) * 2 + n2]); \
    } }                                                                                \
    __builtin_amdgcn_s_setprio(0); } while (0)

#define BAR __builtin_amdgcn_s_barrier()
#define LGKM0 asm volatile("s_waitcnt lgkmcnt(0)" ::: "memory")
#define VMW(n) asm volatile("s_waitcnt vmcnt(" #n ")" ::: "memory")
#define NOPS ((void)0)

// one K-tile = 4 phases; Sk = per-phase stage op, Wk = end-of-phase vm-wait (before BAR)
#define TILE4(bufi, S1, S2, S3, S4, W1, W2, W3, W4) do {                               \
    READ_A(bufi, 0); READ_B(be, bufi, 0);                                              \
    S1; BAR; LGKM0; MMA_Q(0, be, 0); W1; BAR;                                          \
    READ_B(bo, bufi, 1);                                                               \
    S2; BAR; LGKM0; MMA_Q(0, bo, 1); W2; BAR;                                          \
    READ_A(bufi, 1);                                                                   \
    S3; BAR; LGKM0; MMA_Q(1, bo, 1); W3; BAR;                                          \
    S4; BAR; LGKM0; MMA_Q(1, be, 0); W4; BAR; } while (0)

template <typename OutT>
__global__ __launch_bounds__(512, 2)
void gemm256_bt_bias(const __bf16* __restrict__ A, const __bf16* __restrict__ B,
                     const float* __restrict__ bias, OutT* __restrict__ C,
                     int M, int N, int K) {
    __shared__ __align__(16) __bf16 As[2][2][8192];
    __shared__ __align__(16) __bf16 Bs[2][2][8192];

    const int tid = threadIdx.x;
    const int lane = tid & 63, wave = tid >> 6;
    const int lm = lane & 15, quad = lane >> 4, q8 = quad << 3;
    const int wm = wave >> 2, wn = wave & 3;
    const int swz = (lm & 7) << 3;

    // T1: XCD-aware bijective swizzle (grid sizes are % 8 == 0)
    const int nwg = gridDim.x;
    const int wg = (blockIdx.x & 7) * (nwg >> 3) + (blockIdx.x >> 3);
    const int nbx = N >> 8;
    const int m0 = (wg / nbx) << 8;
    const int n0 = (wg % nbx) << 8;

    const int NT = K >> 6, ITER = NT >> 1;

    f32x4 acc[8][4] = {};
    bf16x8 af[4][2], be[2][2], bo[2][2];

    // prologue: tile 0 complete + 3 halves of tile 1 (7 stages = 14 loads).
    // VMW(10) completes stages #1,#2 = the two halves phase 1 reads.
    STAGE_A(0, 0, 0); STAGE_B(0, 0, 0); STAGE_B(0, 1, 0); STAGE_A(0, 1, 0);
    STAGE_A(1, 0, 1); STAGE_B(1, 0, 1); STAGE_B(1, 1, 1);
    VMW(10);
    BAR;

#pragma unroll 1
    for (int i = 0; i < ITER - 1; ++i) {
        const int b = 2 * i + 1, t2 = 2 * i + 2, t3 = 2 * i + 3;
        TILE4(0, STAGE_A(1, 1, b),  STAGE_A(0, 0, t2), STAGE_B(0, 0, t2), STAGE_B(0, 1, t2),
              VMW(10), VMW(10), VMW(10), VMW(10));
        TILE4(1, STAGE_A(0, 1, t2), STAGE_A(1, 0, t3), STAGE_B(1, 0, t3), STAGE_B(1, 1, t3),
              VMW(10), VMW(10), VMW(10), VMW(10));
    }
    // drain iteration: tiles NT-2 (buf0) and NT-1 (buf1); descending waits
    {
        const int b = NT - 1;
        TILE4(0, STAGE_A(1, 1, b), NOPS, NOPS, NOPS, VMW(10), VMW(8), VMW(6), VMW(4));
        TILE4(1, NOPS, NOPS, NOPS, NOPS, VMW(2), VMW(0), NOPS, NOPS);
    }

    // epilogue: same C/D mapping as verified baseline (rows quad*4+r, cols lm)
#pragma unroll
    for (int nf = 0; nf < 4; ++nf) {
        const int col = n0 + (wn << 6) + (nf << 4) + lm;
        const float bj = bias[col];
#pragma unroll
        for (int mf = 0; mf < 8; ++mf) {
            const int mb = m0 + (wm << 7) + (mf << 4) + (quad << 2);
#pragma unroll
            for (int r = 0; r < 4; ++r)
                C[(size_t)(mb + r) * N + col] = (OutT)(acc[mf][nf][r] + bj);
        }
    }
}

// ---------------------------------------------------------------- RMSNorm + 3D RoPE on q,k (in place, bf16)
__global__ void rmsrope(__bf16* __restrict__ qkv, const float* __restrict__ qw,
                        const float* __restrict__ kw) {
    int bn = blockIdx.x;            // b*2048 + n
    int n = bn & 2047;
    int tid = threadIdx.x, wave = tid >> 6, lane = tid & 63;
    int d0 = lane * 2;
    int t = n >> 8, hp = (n >> 4) & 15, wp = n & 15;
    float pos, fi;
    if (d0 < 44)      { pos = (float)t;  fi = (float)(d0 >> 1) * (2.0f / 44.0f); }
    else if (d0 < 86) { pos = (float)hp; fi = (float)((d0 - 44) >> 1) * (2.0f / 42.0f); }
    else              { pos = (float)wp; fi = (float)((d0 - 86) >> 1) * (2.0f / 42.0f); }
    float freq = expf(-fi * 9.210340371976184f);  // 10000^-fi
    float ang = pos * freq, sn, cs;
    sincosf(ang, &sn, &cs);
    float w0q = qw[d0], w1q = qw[d0 + 1], w0k = kw[d0], w1k = kw[d0 + 1];

    for (int h = wave; h < 24; h += 4) {
        size_t base = (size_t)bn * 9216 + h * 128 + d0;
        {
            bf16x2 xv = *(bf16x2*)(qkv + base);
            float x0 = (float)xv.x, x1 = (float)xv.y;
            float ss = x0 * x0 + x1 * x1;
            for (int m = 1; m < 64; m <<= 1) ss += __shfl_xor(ss, m, 64);
            float rr = rsqrtf(ss * (1.0f / 128.0f) + 1e-6f);
            float y0 = x0 * rr * w0q, y1 = x1 * rr * w1q;
            bf16x2 st; st.x = (__bf16)(y0 * cs - y1 * sn); st.y = (__bf16)(y1 * cs + y0 * sn);
            *(bf16x2*)(qkv + base) = st;
        }
        {
            bf16x2 xv = *(bf16x2*)(qkv + base + 3072);
            float x0 = (float)xv.x, x1 = (float)xv.y;
            float ss = x0 * x0 + x1 * x1;
            for (int m = 1; m < 64; m <<= 1) ss += __shfl_xor(ss, m, 64);
            float rr = rsqrtf(ss * (1.0f / 128.0f) + 1e-6f);
            float y0 = x0 * rr * w0k, y1 = x1 * rr * w1k;
            bf16x2 st; st.x = (__bf16)(y0 * cs - y1 * sn); st.y = (__bf16)(y1 * cs + y0 * sn);
            *(bf16x2*)(qkv + base + 3072) = st;
        }
    }
}

// ---------------------------------------------------------------- flash attention (S^T orientation)
// qkv: [4096][9216] bf16 (q/k normed+roped in place; v at 6144+h*128). O: [B][N][C] bf16.
// S^T = K·Q^T: lane holds qrow = lane&15, keys = quad*4+reg (+16j) -> per-lane softmax stats.
__global__ __launch_bounds__(256, 2)
void flash(const __bf16* __restrict__ qkv, __bf16* __restrict__ Oo) {
    __shared__ __align__(16) __bf16 Ks[64 * 136];   // [key][d]
    __shared__ __align__(16) __bf16 VTs[128 * 72];  // [d][key]
    __shared__ __align__(16) __bf16 Ps[128 * 72];   // [q row][key]
    int bh = blockIdx.x >> 4, qt = blockIdx.x & 15;
    int b = bh / 24, h = bh % 24;
    int q0 = qt * 128;
    int tid = threadIdx.x, wave = tid >> 6, lane = tid & 63;
    int lm = lane & 15, q8 = (lane >> 4) * 8, quad = lane >> 4;
    int wb = wave * 32;
    const float sc = 0.08838834764831845f;  // 1/sqrt(128)

    // Q fragments: rows wb+i*16+lm of this q-tile (used as MFMA B operand)
    bf16x8 qf[2][4];
    for (int i = 0; i < 2; ++i)
        for (int kk = 0; kk < 4; ++kk)
            qf[i][kk] = *(const bf16x8*)(qkv + (size_t)(b * 2048 + q0 + wb + i * 16 + lm) * 9216
                                         + h * 128 + kk * 32 + q8);

    float mrow[2] = {-__builtin_inff(), -__builtin_inff()};
    float lrow[2] = {0.f, 0.f};
    f32x4 oacc[2][8] = {};   // oacc[i][ct]: d = ct*16+quad*4+reg, qrow = wb+i*16+lm

    for (int nt = 0; nt < 32; ++nt) {
        int n0 = nt * 64;
        __syncthreads();
        for (int r = 0; r < 4; ++r) {
            int c = r * 256 + tid;                  // 0..1023
            int krow = c >> 4, kch = (c & 15) * 8;  // K: 64 x 16 chunks
            *(uint4*)(Ks + krow * 136 + kch) =
                *(const uint4*)(qkv + (size_t)(b * 2048 + n0 + krow) * 9216 + 3072 + h * 128 + kch);
            int vkey = c & 63, vch = (c >> 6) * 8;  // V: transpose on stage
            bf16x8 vv = *(const bf16x8*)(qkv + (size_t)(b * 2048 + n0 + vkey) * 9216 + 6144 + h * 128 + vch);
            for (int j = 0; j < 8; ++j)
                VTs[(vch + j) * 72 + vkey] = vv[j];
        }
        __syncthreads();

        // S^T = K Q^T : s[i][j] holds keys j*16+quad*4+reg for qrow wb+i*16+lm
        f32x4 s[2][4] = {};
        for (int kk = 0; kk < 4; ++kk) {
            bf16x8 bk[4];
            for (int j = 0; j < 4; ++j)
                bk[j] = *(const bf16x8*)(Ks + (j * 16 + lm) * 136 + kk * 32 + q8);
            for (int i = 0; i < 2; ++i)
                for (int j = 0; j < 4; ++j)
                    s[i][j] = MFMA16(bk[j], qf[i][kk], s[i][j]);
        }
        // online softmax: all 16 key-values for a row are in-lane; cross-quad = 2 shuffles
        for (int i = 0; i < 2; ++i) {
            float mx = -__builtin_inff();
            for (int j = 0; j < 4; ++j)
                for (int r = 0; r < 4; ++r)
                    mx = fmaxf(mx, s[i][j][r]);
            mx *= sc;
            mx = fmaxf(mx, __shfl_xor(mx, 16, 64));
            mx = fmaxf(mx, __shfl_xor(mx, 32, 64));
            float mn = fmaxf(mrow[i], mx);
            float alpha = __expf(mrow[i] - mn);
            mrow[i] = mn;
            float rs = 0.f;
            for (int j = 0; j < 4; ++j) {
                bf16x4 pw;
                for (int r = 0; r < 4; ++r) {
                    float p = __expf(s[i][j][r] * sc - mn);
                    rs += p;
                    pw[r] = (__bf16)p;
                }
                *(bf16x4*)(Ps + (wb + i * 16 + lm) * 72 + j * 16 + quad * 4) = pw;
            }
            rs += __shfl_xor(rs, 16, 64);
            rs += __shfl_xor(rs, 32, 64);
            lrow[i] = lrow[i] * alpha + rs;
            if (__any(alpha != 1.0f))
                for (int ct = 0; ct < 8; ++ct) oacc[i][ct] *= alpha;
        }
        // O^T += V^T P^T (P rows wb..wb+31 are wave-private)
        for (int kk = 0; kk < 2; ++kk) {
            bf16x8 ap[2];
            for (int i = 0; i < 2; ++i)
                ap[i] = *(const bf16x8*)(Ps + (wb + i * 16 + lm) * 72 + kk * 32 + q8);
            for (int ct = 0; ct < 8; ++ct) {
                bf16x8 bv = *(const bf16x8*)(VTs + (ct * 16 + lm) * 72 + kk * 32 + q8);
                for (int i = 0; i < 2; ++i)
                    oacc[i][ct] = MFMA16(bv, ap[i], oacc[i][ct]);
            }
        }
    }
    // epilogue: O /= l; lane owns qrow = wb+i*16+lm, d = ct*16+quad*4+[0..3]
    for (int i = 0; i < 2; ++i) {
        float inv = 1.0f / lrow[i];
        int row = q0 + wb + i * 16 + lm;
        size_t base = ((size_t)b * 2048 + row) * 3072 + h * 128 + quad * 4;
        for (int ct = 0; ct < 8; ++ct) {
            bf16x4 ov;
            for (int r = 0; r < 4; ++r) ov[r] = (__bf16)(oacc[i][ct][r] * inv);
            *(bf16x4*)(Oo + base + ct * 16) = ov;
        }
    }
}

// ---------------------------------------------------------------- launch
extern "C" void kernel_launch(void* const* d_in, const int* in_sizes, int n_in,
                              void* d_out, int out_size, void* d_ws, size_t ws_size,
                              hipStream_t stream) {
    const float* x      = (const float*)d_in[0];
    const float* qkv_w  = (const float*)d_in[1];
    const float* qkv_b  = (const float*)d_in[2];
    const float* qnw    = (const float*)d_in[3];
    const float* knw    = (const float*)d_in[4];
    const float* proj_w = (const float*)d_in[5];
    const float* proj_b = (const float*)d_in[6];
    float* out = (float*)d_out;
    char* ws = (char*)d_ws;

    // ws layout (bytes), total 176,160,768
    __bf16* xb   = (__bf16*)(ws + 0);           //  25,165,824  x bf16 (dead after gemm1)
    __bf16* attn = (__bf16*)(ws + 0);           //  alias: flash output [4096][3072] bf16
    __bf16* w1b  = (__bf16*)(ws + 25165824);    //  56,623,104  qkv_w bf16
    __bf16* w2b  = (__bf16*)(ws + 81788928);    //  18,874,368  proj_w bf16
    __bf16* qkvb = (__bf16*)(ws + 100663296);   //  75,497,472  qkv bf16 [4096][9216]

    pack_bf16<<<12288, 256, 0, stream>>>(x, xb, 3145728);
    pack_bf16<<<27648, 256, 0, stream>>>(qkv_w, w1b, 7077888);
    pack_bf16<<<9216, 256, 0, stream>>>(proj_w, w2b, 2359296);

    // QKV: [4096,3072] x [9216,3072]^T -> grid 16*36 = 576 blocks (%8==0)
    gemm256_bt_bias<__bf16><<<576, 512, 0, stream>>>(xb, w1b, qkv_b, qkvb, 4096, 9216, 3072);

    rmsrope<<<4096, 256, 0, stream>>>(qkvb, qnw, knw);

    flash<<<768, 256, 0, stream>>>(qkvb, attn);

    // proj: [4096,3072] x [3072,3072]^T -> grid 16*12 = 192 blocks (%8==0)
    gemm256_bt_bias<float><<<192, 512, 0, stream>>>(attn, w2b, proj_b, out, 4096, 3072, 3072);
}